// Round 2
// baseline (17564.453 us; speedup 1.0000x reference)
//
#include <hip/hip_runtime.h>
#include <stdint.h>

// DecoderRNN R17: R15 semantics (producer drain + REAL flags) + L2-CACHED
// h-broadcast reads.
//  R16 post-mortem: removing producer drains was NEUTRAL -> hops are
//  throughput-bound, not flag-latency-bound. Per step, 4 co-XCD consumer WGs
//  each pull identical 128KB h data via sc0sc1 (LLC-direct, zero L2 reuse):
//  ~16MB/step of serialized fabric traffic. R17 makes the broadcast loads
//  L2-cacheable: consumer observes the (real, drained) flag, issues ONE
//  agent-acquire fence (buffer_inv: drops stale clean lines, keeps dirty),
//  then loads h with plain cached dwordx4 -> first co-XCD WG misses to LLC,
//  the other 3 hit L2. Fabric read traffic ~16MB -> ~4.4MB per step.
//  gh1 stays sc0sc1 (single consumer per slot, nothing to share).
//  Flag polls / y-partial reads stay agent-atomic loads (bypass L2).
//  Epoch tags removed (numerics bit-identical to R15).

#define NWG 128
#define NT  256
#define TT  1024

typedef unsigned short ushort;
typedef unsigned int   uint;
typedef unsigned long long ull;
typedef __attribute__((ext_vector_type(8))) short short8;
typedef __attribute__((ext_vector_type(4))) float f32x4;
typedef __attribute__((ext_vector_type(4))) uint  uint4v;

struct __align__(16) Smem {
  ushort wpl[2][48*520];
  float  gictx[3*16*68];
  float  wcol[3][16];
  float  bsumR[16], bsumZ[16], binN[16], bhnN[16];
  float  bo1v[16], wo2v[16];
  float  prevS[64];
};

__device__ __forceinline__ float sigm(float x){ return 1.f/(1.f + expf(-x)); }
__device__ __forceinline__ float bf2f(ushort h){ return __uint_as_float(((uint)h)<<16); }
__device__ __forceinline__ ushort bfrnd(float x){
  uint u = __float_as_uint(x);
  return (ushort)((u + 0x7fffu + ((u>>16)&1u)) >> 16);
}
__device__ __forceinline__ float unpk(uint p){
  return bf2f((ushort)(p >> 16)) + bf2f((ushort)(p & 0xffffu));
}
__device__ __forceinline__ uint pkh(float h){
  ushort hb = bfrnd(h);
  ushort lb = bfrnd(h - bf2f(hb));
  return ((uint)hb << 16) | (uint)lb;
}
__device__ __forceinline__ short8 hi8(uint4v a, uint4v b){
  uint d0 = __builtin_amdgcn_perm(a.y, a.x, 0x07060302u);
  uint d1 = __builtin_amdgcn_perm(a.w, a.z, 0x07060302u);
  uint d2 = __builtin_amdgcn_perm(b.y, b.x, 0x07060302u);
  uint d3 = __builtin_amdgcn_perm(b.w, b.z, 0x07060302u);
  return __builtin_bit_cast(short8, (uint4v){d0,d1,d2,d3});
}
__device__ __forceinline__ short8 lo8(uint4v a, uint4v b){
  uint d0 = __builtin_amdgcn_perm(a.y, a.x, 0x05040100u);
  uint d1 = __builtin_amdgcn_perm(a.w, a.z, 0x05040100u);
  uint d2 = __builtin_amdgcn_perm(b.y, b.x, 0x05040100u);
  uint d3 = __builtin_amdgcn_perm(b.w, b.z, 0x05040100u);
  return __builtin_bit_cast(short8, (uint4v){d0,d1,d2,d3});
}
#define SWP(p, v)  (void)__hip_atomic_exchange((uint*)(p), (uint)(v), __ATOMIC_RELAXED, __HIP_MEMORY_SCOPE_AGENT)
#define SWPF(p, v) SWP((p), __float_as_uint(v))
#define ALD1(p)    __hip_atomic_load((const uint*)(p), __ATOMIC_RELAXED, __HIP_MEMORY_SCOPE_AGENT)
#define ALDF(p)    __uint_as_float(ALD1(p))
#define FADDI(p)   (void)__hip_atomic_fetch_add((p), 1, __ATOMIC_RELAXED, __HIP_MEMORY_SCOPE_AGENT)

// init/final global barrier (epoch-monotonic)
__device__ __forceinline__ void gbar(int* slots, int* epoch, int w, int tid, int e){
  __syncthreads();
  if (tid == 0)
    __hip_atomic_store(&slots[w], e, __ATOMIC_RELEASE, __HIP_MEMORY_SCOPE_AGENT);
  if (w == 0 && tid < 64){
    for(;;){
      int m0 = __hip_atomic_load(&slots[tid*2+0], __ATOMIC_RELAXED, __HIP_MEMORY_SCOPE_AGENT);
      int m1 = __hip_atomic_load(&slots[tid*2+1], __ATOMIC_RELAXED, __HIP_MEMORY_SCOPE_AGENT);
      if (__all(min(m0,m1) >= e)) break;
      __builtin_amdgcn_s_sleep(1);
    }
    if (tid == 0){
      __builtin_amdgcn_fence(__ATOMIC_ACQUIRE, "agent");
      __hip_atomic_store(epoch, e, __ATOMIC_RELEASE, __HIP_MEMORY_SCOPE_AGENT);
    }
  }
  if (tid == 0){
    while (__hip_atomic_load(epoch, __ATOMIC_RELAXED, __HIP_MEMORY_SCOPE_AGENT) < e)
      __builtin_amdgcn_s_sleep(1);
    __builtin_amdgcn_fence(__ATOMIC_ACQUIRE, "agent");
  }
  __syncthreads();
}

__device__ __forceinline__ void drain_sync(){
  __builtin_amdgcn_s_waitcnt(0);
  __syncthreads();
}
// flag poll: 1 lane, 1 dword, no fence (for agent-atomic data paths)
__device__ __forceinline__ void waitmail(const int* w, int target, int tid){
  if (tid == 0)
    while ((int)ALD1(w) < target) __builtin_amdgcn_s_sleep(1);
  __syncthreads();
}
// flag poll + agent acquire: invalidates stale L1/L2 lines so following
// PLAIN cached loads refill fresh from LLC (producer drained before flag)
__device__ __forceinline__ void waitmail_acq(const int* w, int target, int tid){
  if (tid == 0){
    while ((int)ALD1(w) < target) __builtin_amdgcn_s_sleep(1);
    __builtin_amdgcn_fence(__ATOMIC_ACQUIRE, "agent");
  }
  __syncthreads();
}

// coherent LLC-direct 16B load (sc0 sc1) -- gh1 path only
#define LD1SC(dst, addr) \
  asm volatile("global_load_dwordx4 %0, %1, off sc0 sc1" : "=v"(dst) : "v"(addr));
#define WB3(a,b,c) asm volatile("s_waitcnt vmcnt(0)" : "+v"(a),"+v"(b),"+v"(c));
#define VMBAR8(a,b,c,d,e,f,g,h) \
  asm volatile("s_waitcnt vmcnt(0)" \
               : "+v"(a),"+v"(b),"+v"(c),"+v"(d),"+v"(e),"+v"(f),"+v"(g),"+v"(h));

// L2-CACHED 16B loads for the h broadcast (freshness via waitmail_acq)
#define LDC(P, i) \
  asm volatile("global_load_dwordx4 %0, %1, off" \
               : "=v"(pa##i) : "v"((P) + aoff + (i)*32)); \
  asm volatile("global_load_dwordx4 %0, %1, off" \
               : "=v"(pb##i) : "v"((P) + aoff + (i)*32 + 4));
#define DECL_LOADS(P) \
  uint4v pa0,pa1,pa2,pa3,pa4,pa5,pa6,pa7,pa8,pa9,pa10,pa11,pa12,pa13,pa14,pa15; \
  uint4v pb0,pb1,pb2,pb3,pb4,pb5,pb6,pb7,pb8,pb9,pb10,pb11,pb12,pb13,pb14,pb15; \
  LDC(P,0) LDC(P,1) LDC(P,2) LDC(P,3) LDC(P,4) LDC(P,5) LDC(P,6) LDC(P,7) \
  LDC(P,8) LDC(P,9) LDC(P,10) LDC(P,11) LDC(P,12) LDC(P,13) LDC(P,14) LDC(P,15) \
  VMBAR8(pa0,pb0,pa1,pb1,pa2,pb2,pa3,pb3) \
  VMBAR8(pa4,pb4,pa5,pb5,pa6,pb6,pa7,pb7) \
  VMBAR8(pa8,pb8,pa9,pb9,pa10,pb10,pa11,pb11) \
  VMBAR8(pa12,pb12,pa13,pb13,pa14,pb14,pa15,pb15)

#define MS3(i) { \
  short8 AH_ = hi8(pa##i, pb##i); \
  short8 AL_ = lo8(pa##i, pb##i); \
  const int ko_ = (i)*32 + q*8; \
  short8 bh_ = *(const short8*)(&S.wpl[0][(col)*520 + ko_]); \
  short8 bl_ = *(const short8*)(&S.wpl[1][(col)*520 + ko_]); \
  acc0 = __builtin_amdgcn_mfma_f32_16x16x32_bf16(AH_, bh_, acc0, 0,0,0); \
  acc0 = __builtin_amdgcn_mfma_f32_16x16x32_bf16(AL_, bh_, acc0, 0,0,0); \
  acc0 = __builtin_amdgcn_mfma_f32_16x16x32_bf16(AH_, bl_, acc0, 0,0,0); \
  bh_ = *(const short8*)(&S.wpl[0][(16+col)*520 + ko_]); \
  bl_ = *(const short8*)(&S.wpl[1][(16+col)*520 + ko_]); \
  acc1 = __builtin_amdgcn_mfma_f32_16x16x32_bf16(AH_, bh_, acc1, 0,0,0); \
  acc1 = __builtin_amdgcn_mfma_f32_16x16x32_bf16(AL_, bh_, acc1, 0,0,0); \
  acc1 = __builtin_amdgcn_mfma_f32_16x16x32_bf16(AH_, bl_, acc1, 0,0,0); \
  bh_ = *(const short8*)(&S.wpl[0][(32+col)*520 + ko_]); \
  bl_ = *(const short8*)(&S.wpl[1][(32+col)*520 + ko_]); \
  acc2 = __builtin_amdgcn_mfma_f32_16x16x32_bf16(AH_, bh_, acc2, 0,0,0); \
  acc2 = __builtin_amdgcn_mfma_f32_16x16x32_bf16(AL_, bh_, acc2, 0,0,0); \
  acc2 = __builtin_amdgcn_mfma_f32_16x16x32_bf16(AH_, bl_, acc2, 0,0,0); }

#define MS1(i) { \
  short8 AH_ = hi8(pa##i, pb##i); \
  short8 AL_ = lo8(pa##i, pb##i); \
  const int ko_ = (i)*32 + q*8; \
  short8 bh_ = *(const short8*)(&S.wpl[0][(col)*520 + ko_]); \
  short8 bl_ = *(const short8*)(&S.wpl[1][(col)*520 + ko_]); \
  acc0 = __builtin_amdgcn_mfma_f32_16x16x32_bf16(AH_, bh_, acc0, 0,0,0); \
  acc0 = __builtin_amdgcn_mfma_f32_16x16x32_bf16(AL_, bh_, acc0, 0,0,0); \
  acc0 = __builtin_amdgcn_mfma_f32_16x16x32_bf16(AH_, bl_, acc0, 0,0,0); }

#define RUN16(M) M(0) M(1) M(2) M(3) M(4) M(5) M(6) M(7) \
                 M(8) M(9) M(10) M(11) M(12) M(13) M(14) M(15)

extern "C" __global__ void __launch_bounds__(NT, 1)
decoder_rnn(const float* __restrict__ ctx,   // [64][512]
            const float* __restrict__ Wih0,  // [1536][513] (row stride 513!)
            const float* __restrict__ Whh0,
            const float* __restrict__ bih0,
            const float* __restrict__ bhh0g,
            const float* __restrict__ Wih1,
            const float* __restrict__ Whh1,
            const float* __restrict__ bih1g,
            const float* __restrict__ bhh1g,
            const float* __restrict__ Wo1,
            const float* __restrict__ bo1g,
            const float* __restrict__ Wo2,
            const float* __restrict__ bo2g,
            float* __restrict__ out,         // [64*1024 y][65536 h_i]
            float* __restrict__ ws)
{
  extern __shared__ char smem_raw[];
  Smem& S = *reinterpret_cast<Smem*>(smem_raw);
  const int tid = threadIdx.x;
  const int wg  = blockIdx.x;

  uint*  hpk    = (uint*)ws;                 // h0pk 2x32768 | h1pk 32768
  float* gh1raw = (float*)ws + 98304;        // 32*3072
  float* yout   = (float*)ws + 196608;       // 2 x 2048
  int*   ibase  = (int*)((float*)ws + 200704);
  int*   gslots = ibase;                     // [128] gbar
  int*   epoch  = ibase + 128;
  int*   mbox   = ibase + 256;               // 128 lines x 32 ints (128B/line)

  const float bo2v = bo2g[0];

  // ---------------- init (swaps -> LLC) ----------------
  for (int i = wg*NT + tid; i < 200704; i += NWG*NT)
    SWP((uint*)ws + i, 0u);
  if (wg == 0)
    for (int i = tid; i < NWG*32; i += NT) SWP(mbox + i, 0);

  const int role = wg >> 5;
  const int j    = wg & 31;
  if (role != 3){
    const float* Wsrc = (role == 0) ? Whh0 : (role == 1) ? Whh1 : Wih1;
    for (int i = tid; i < 48*512; i += NT){
      int r = i >> 9, k = i & 511;
      int g = r >> 4, n = r & 15;
      float wv = Wsrc[(size_t)(g*512 + 16*j + n)*512 + k];
      ushort hh = bfrnd(wv);
      S.wpl[0][r*520 + k] = hh;
      S.wpl[1][r*520 + k] = bfrnd(wv - bf2f(hh));
    }
  } else {
    for (int i = tid; i < 16*512; i += NT){
      int r = i >> 9, k = i & 511;
      float wv = Wo1[(size_t)(16*j + r)*512 + k];
      ushort hh = bfrnd(wv);
      S.wpl[0][r*520 + k] = hh;
      S.wpl[1][r*520 + k] = bfrnd(wv - bf2f(hh));
    }
    if (tid < 16){ S.bo1v[tid] = bo1g[16*j + tid]; S.wo2v[tid] = Wo2[16*j + tid]; }
  }
  if (role == 0){
    if (tid < 48){
      int g = tid >> 4, n = tid & 15;
      S.wcol[g][n] = Wih0[(size_t)(g*512 + 16*j + n)*513 + 512];
    }
    if (tid < 16) S.bhnN[tid] = bhh0g[2*512 + 16*j + tid];
    for (int idx = tid; idx < 3072; idx += NT){
      int r = idx >> 6, b = idx & 63;
      int g = r >> 4, n = r & 15;
      int grow = g*512 + 16*j + n;
      const float* wr = Wih0 + (size_t)grow*513;
      const float* cx = ctx  + (size_t)b*512;
      float s = bih0[grow];
      if (g < 2) s += bhh0g[grow];
      #pragma unroll 4
      for (int k = 0; k < 512; ++k) s += wr[k]*cx[k];
      S.gictx[g*1088 + n*68 + b] = s;
    }
  }
  if (role == 2 && tid < 16){
    int n = tid;
    S.bsumR[n] = bih1g[16*j + n]       + bhh1g[16*j + n];
    S.bsumZ[n] = bih1g[512 + 16*j + n] + bhh1g[512 + 16*j + n];
    S.binN[n]  = bih1g[1024 + 16*j + n];
    S.bhnN[n]  = bhh1g[1024 + 16*j + n];
  }

  gbar(gslots, epoch, wg, tid, 1);

  int* myline = mbox + wg*32;

  const int v   = tid >> 6;
  const int l   = tid & 63;
  const int q   = l >> 4;
  const int col = l & 15;
  const int aoff = (16*v + col)*512 + q*8;
  const int b0w  = 16*v + 4*q;
  const int ng   = 16*j + col;

  if (role == 0){
    float hc0 = 0.f, hc1 = 0.f, hc2 = 0.f, hc3 = 0.f;   // carried h0-old
    for (int t = 0; t < TT; ++t){
      const int r0 = t & 1, w0 = r0 ^ 1;
      waitmail_acq(myline + 0, 32*t, tid);   // h0[t-1] at LLC; inv L1/L2
      const uint* rP = hpk + r0*32768;
      uint*       wP = hpk + w0*32768;
      f32x4 acc0={0,0,0,0}, acc1={0,0,0,0}, acc2={0,0,0,0};
      DECL_LOADS(rP)
      RUN16(MS3)
      waitmail(myline + 1, 32*t, tid);       // y[t-1] partials at LLC
      if (tid < 64){
        float s = 0.f;
        if (t > 0){
          const float* yp = yout + ((t-1)&1)*2048 + tid;
          #pragma unroll
          for (int jj = 0; jj < 32; ++jj) s += ALDF(yp + jj*64);
        }
        float pv = fmaxf(s + bo2v, 0.f);
        S.prevS[tid] = pv;
        if (wg == 0 && t > 0) out[(size_t)tid*TT + (t-1)] = pv;
      }
      __syncthreads();
      f32x4 pv4 = *(const f32x4*)&S.prevS[b0w];
      f32x4 gR = *(const f32x4*)&S.gictx[0*1088 + col*68 + b0w];
      f32x4 gZ = *(const f32x4*)&S.gictx[1*1088 + col*68 + b0w];
      f32x4 gN = *(const f32x4*)&S.gictx[2*1088 + col*68 + b0w];
      float wc0 = S.wcol[0][col], wc1 = S.wcol[1][col], wc2 = S.wcol[2][col];
      float bhn = S.bhnN[col];
      #define E0(i, HC) { \
        float rr = sigm(gR[i] + pv4[i]*wc0 + acc0[i]); \
        float zz = sigm(gZ[i] + pv4[i]*wc1 + acc1[i]); \
        float nn = tanhf(gN[i] + pv4[i]*wc2 + rr*(acc2[i] + bhn)); \
        float h = (1.f-zz)*nn + zz*HC; \
        HC = h; \
        SWP(wP + (size_t)(b0w+(i))*512 + ng, pkh(h)); }
      E0(0,hc0) E0(1,hc1) E0(2,hc2) E0(3,hc3)
      #undef E0
      drain_sync();
      if (tid < 64) FADDI(mbox + ((tid < 32) ? tid : tid + 32)*32 + 0);
    }
  } else if (role == 1){
    const uint* hp1 = hpk + 65536;
    for (int t = 0; t < TT; ++t){
      waitmail_acq(myline + 0, 32*t, tid);   // h1[t-1] at LLC; inv L1/L2
      f32x4 acc0={0,0,0,0}, acc1={0,0,0,0}, acc2={0,0,0,0};
      DECL_LOADS(hp1)
      RUN16(MS3)
      float* gp = gh1raw + (size_t)j*3072 + v*256 + l*4;
      #pragma unroll
      for (int e = 0; e < 4; ++e){
        SWPF(gp + e,        acc0[e]);
        SWPF(gp + 1024 + e, acc1[e]);
        SWPF(gp + 2048 + e, acc2[e]);
      }
      drain_sync();
      if (tid < 32) FADDI(mbox + (64 + tid)*32 + 1);
    }
  } else if (role == 2){
    uint* p1 = hpk + 65536;
    float hc0 = 0.f, hc1 = 0.f, hc2 = 0.f, hc3 = 0.f;   // carried h1-old
    for (int t = 0; t < TT; ++t){
      const int w0 = (t & 1) ^ 1;
      waitmail(myline + 0, 32*(t+1), tid);       // h0[t] at LLC
      waitmail_acq(myline + 1, 32*(t+1), tid);   // gh1[t]; inv L1/L2 (covers h0)
      const uint* rP = hpk + w0*32768;
      const float* gp = gh1raw + (size_t)j*3072 + v*256 + l*4;
      // issue gh1 loads first; they complete under DECL_LOADS' vmcnt(0)
      uint4v hRv, hZv, hNv;
      LD1SC(hRv, (const uint*)(gp + 0))
      LD1SC(hZv, (const uint*)(gp + 1024))
      LD1SC(hNv, (const uint*)(gp + 2048))
      f32x4 acc0={0,0,0,0}, acc1={0,0,0,0}, acc2={0,0,0,0};
      DECL_LOADS(rP)
      WB3(hRv, hZv, hNv)
      RUN16(MS3)
      f32x4 hR = __builtin_bit_cast(f32x4, hRv);
      f32x4 hZ = __builtin_bit_cast(f32x4, hZv);
      f32x4 hN = __builtin_bit_cast(f32x4, hNv);
      float bsR = S.bsumR[col], bsZ = S.bsumZ[col], biN = S.binN[col], bhN = S.bhnN[col];
      #define E1(i, HC) { \
        float r1 = sigm(acc0[i] + hR[i] + bsR); \
        float z1 = sigm(acc1[i] + hZ[i] + bsZ); \
        float n1 = tanhf(acc2[i] + biN + r1*(hN[i] + bhN)); \
        float h = (1.f-z1)*n1 + z1*HC; \
        HC = h; \
        SWP(p1 + (size_t)(b0w+(i))*512 + ng, pkh(h)); }
      E1(0,hc0) E1(1,hc1) E1(2,hc2) E1(3,hc3)
      #undef E1
      drain_sync();
      if (tid < 64) FADDI(mbox + ((tid < 32) ? (96 + tid) : tid)*32 + 0);
    }
  } else {
    const uint* hp1 = hpk + 65536;
    for (int t = 0; t < TT; ++t){
      waitmail_acq(myline + 0, 32*(t+1), tid);   // h1[t] at LLC; inv L1/L2
      f32x4 acc0={0,0,0,0};
      DECL_LOADS(hp1)
      RUN16(MS1)
      float s0 = S.wo2v[col]*fmaxf(acc0[0] + S.bo1v[col], 0.f);
      float s1 = S.wo2v[col]*fmaxf(acc0[1] + S.bo1v[col], 0.f);
      float s2 = S.wo2v[col]*fmaxf(acc0[2] + S.bo1v[col], 0.f);
      float s3 = S.wo2v[col]*fmaxf(acc0[3] + S.bo1v[col], 0.f);
      #pragma unroll
      for (int d = 1; d < 16; d <<= 1){
        s0 += __shfl_xor(s0, d);
        s1 += __shfl_xor(s1, d);
        s2 += __shfl_xor(s2, d);
        s3 += __shfl_xor(s3, d);
      }
      if (col == 0){
        float* rp = yout + (t&1)*2048 + j*64 + b0w;
        SWPF(rp + 0, s0); SWPF(rp + 1, s1); SWPF(rp + 2, s2); SWPF(rp + 3, s3);
      }
      drain_sync();
      if (tid < 32) FADDI(mbox + tid*32 + 1);
    }
  }

  // ---------------- finale: one global release/acquire barrier ------------
  gbar(gslots, epoch, wg, tid, 2);
  if (wg == 0 && tid < 64){
    float s = 0.f;
    const float* yp = yout + 2048 + tid;     // parity of t=1023 is 1
    #pragma unroll
    for (int jj = 0; jj < 32; ++jj) s += ALDF(yp + jj*64);
    out[(size_t)tid*TT + 1023] = fmaxf(s + bo2v, 0.f);
  }
  #pragma unroll
  for (int k = 0; k < 2; ++k){
    int g = wg*512 + k*256 + tid;
    if (g < 32768) out[65536 + g] = unpk(hpk[g]);            // h0 final in buf0
    else           out[65536 + g] = unpk(hpk[65536 + (g - 32768)]);
  }
}

extern "C" void kernel_launch(void* const* d_in, const int* in_sizes, int n_in,
                              void* d_out, int out_size, void* d_ws, size_t ws_size,
                              hipStream_t stream){
  const float* ctx   = (const float*)d_in[0];
  const float* Wih0  = (const float*)d_in[2];
  const float* Whh0  = (const float*)d_in[3];
  const float* bih0  = (const float*)d_in[4];
  const float* bhh0  = (const float*)d_in[5];
  const float* Wih1  = (const float*)d_in[6];
  const float* Whh1  = (const float*)d_in[7];
  const float* bih1  = (const float*)d_in[8];
  const float* bhh1  = (const float*)d_in[9];
  const float* Wo1   = (const float*)d_in[10];
  const float* bo1   = (const float*)d_in[11];
  const float* Wo2   = (const float*)d_in[12];
  const float* bo2   = (const float*)d_in[13];

  (void)in_sizes; (void)n_in; (void)out_size; (void)ws_size;

  (void)hipFuncSetAttribute((const void*)decoder_rnn,
                            hipFuncAttributeMaxDynamicSharedMemorySize,
                            (int)sizeof(Smem));

  decoder_rnn<<<NWG, NT, sizeof(Smem), stream>>>(
      ctx, Wih0, Whh0, bih0, bhh0, Wih1, Whh1, bih1, bhh1,
      Wo1, bo1, Wo2, bo2, (float*)d_out, (float*)d_ws);
}

// Round 3
// 17268.648 us; speedup vs baseline: 1.0171x; 1.0171x over previous
//
#include <hip/hip_runtime.h>
#include <stdint.h>

// DecoderRNN R18: R15 semantics (producer drain + REAL flags, sc0sc1 LLC-direct
// data path) with the ENTIRE data path converted from per-lane 4B ATOMICS to
// COALESCED plain sc0/sc1 stores+loads.
//  R16 (drain/flag RTT trim): neutral. R17 (L2-cached broadcast): neutral.
//  Counters show 3.4GB memory-side traffic vs ~0.7GB logical -> ~4x write
//  amplification from ~166K uncoalesced 4B atomic transactions per step
//  (h0 32K + h1 32K + gh1 98K + yout 2K swaps, + 2K atomic y-loads).
//  Atomics don't coalesce; plain sc0sc1 stores do (64B/line, 1KB/instr) and
//  have IDENTICAL visibility (bypass L1/L2, execute at coherence point).
//  Flag discipline unchanged: producer s_waitcnt vmcnt(0) drain -> FADDI flag
//  -> consumer poll -> sc0sc1 loads. Atomics remain ONLY for mbox flags/gbar.

#define NWG 128
#define NT  256
#define TT  1024

typedef unsigned short ushort;
typedef unsigned int   uint;
typedef unsigned long long ull;
typedef __attribute__((ext_vector_type(8))) short short8;
typedef __attribute__((ext_vector_type(4))) float f32x4;
typedef __attribute__((ext_vector_type(4))) uint  uint4v;

struct __align__(16) Smem {
  ushort wpl[2][48*520];
  float  gictx[3*16*68];
  float  wcol[3][16];
  float  bsumR[16], bsumZ[16], binN[16], bhnN[16];
  float  bo1v[16], wo2v[16];
  float  prevS[64];
};

__device__ __forceinline__ float sigm(float x){ return 1.f/(1.f + expf(-x)); }
__device__ __forceinline__ float bf2f(ushort h){ return __uint_as_float(((uint)h)<<16); }
__device__ __forceinline__ ushort bfrnd(float x){
  uint u = __float_as_uint(x);
  return (ushort)((u + 0x7fffu + ((u>>16)&1u)) >> 16);
}
__device__ __forceinline__ float unpk(uint p){
  return bf2f((ushort)(p >> 16)) + bf2f((ushort)(p & 0xffffu));
}
__device__ __forceinline__ uint pkh(float h){
  ushort hb = bfrnd(h);
  ushort lb = bfrnd(h - bf2f(hb));
  return ((uint)hb << 16) | (uint)lb;
}
__device__ __forceinline__ short8 hi8(uint4v a, uint4v b){
  uint d0 = __builtin_amdgcn_perm(a.y, a.x, 0x07060302u);
  uint d1 = __builtin_amdgcn_perm(a.w, a.z, 0x07060302u);
  uint d2 = __builtin_amdgcn_perm(b.y, b.x, 0x07060302u);
  uint d3 = __builtin_amdgcn_perm(b.w, b.z, 0x07060302u);
  return __builtin_bit_cast(short8, (uint4v){d0,d1,d2,d3});
}
__device__ __forceinline__ short8 lo8(uint4v a, uint4v b){
  uint d0 = __builtin_amdgcn_perm(a.y, a.x, 0x05040100u);
  uint d1 = __builtin_amdgcn_perm(a.w, a.z, 0x05040100u);
  uint d2 = __builtin_amdgcn_perm(b.y, b.x, 0x05040100u);
  uint d3 = __builtin_amdgcn_perm(b.w, b.z, 0x05040100u);
  return __builtin_bit_cast(short8, (uint4v){d0,d1,d2,d3});
}
#define SWP(p, v)  (void)__hip_atomic_exchange((uint*)(p), (uint)(v), __ATOMIC_RELAXED, __HIP_MEMORY_SCOPE_AGENT)
#define ALD1(p)    __hip_atomic_load((const uint*)(p), __ATOMIC_RELAXED, __HIP_MEMORY_SCOPE_AGENT)
#define ALDF(p)    __uint_as_float(ALD1(p))
#define FADDI(p)   (void)__hip_atomic_fetch_add((p), 1, __ATOMIC_RELAXED, __HIP_MEMORY_SCOPE_AGENT)

// init/final global barrier (epoch-monotonic)
__device__ __forceinline__ void gbar(int* slots, int* epoch, int w, int tid, int e){
  __syncthreads();
  if (tid == 0)
    __hip_atomic_store(&slots[w], e, __ATOMIC_RELEASE, __HIP_MEMORY_SCOPE_AGENT);
  if (w == 0 && tid < 64){
    for(;;){
      int m0 = __hip_atomic_load(&slots[tid*2+0], __ATOMIC_RELAXED, __HIP_MEMORY_SCOPE_AGENT);
      int m1 = __hip_atomic_load(&slots[tid*2+1], __ATOMIC_RELAXED, __HIP_MEMORY_SCOPE_AGENT);
      if (__all(min(m0,m1) >= e)) break;
      __builtin_amdgcn_s_sleep(1);
    }
    if (tid == 0){
      __builtin_amdgcn_fence(__ATOMIC_ACQUIRE, "agent");
      __hip_atomic_store(epoch, e, __ATOMIC_RELEASE, __HIP_MEMORY_SCOPE_AGENT);
    }
  }
  if (tid == 0){
    while (__hip_atomic_load(epoch, __ATOMIC_RELAXED, __HIP_MEMORY_SCOPE_AGENT) < e)
      __builtin_amdgcn_s_sleep(1);
    __builtin_amdgcn_fence(__ATOMIC_ACQUIRE, "agent");
  }
  __syncthreads();
}

__device__ __forceinline__ void drain_sync(){
  __builtin_amdgcn_s_waitcnt(0);
  __syncthreads();
}
// consumer poll: 1 lane, 1 dword, NO fence (loop data path is LLC-coherent)
__device__ __forceinline__ void waitmail(const int* w, int target, int tid){
  if (tid == 0)
    while ((int)ALD1(w) < target) __builtin_amdgcn_s_sleep(1);
  __syncthreads();
}
__device__ __forceinline__ void finfence(int tid){
  if (tid == 0) __builtin_amdgcn_fence(__ATOMIC_ACQUIRE, "agent");
  __syncthreads();
}

// coherent LLC-direct loads/stores (sc0 sc1 = bypass L1+L2, COALESCED)
#define LD1SC(dst, addr) \
  asm volatile("global_load_dwordx4 %0, %1, off sc0 sc1" : "=v"(dst) : "v"(addr));
#define LD1SCD(dst, addr) \
  asm volatile("global_load_dword %0, %1, off sc0 sc1" : "=v"(dst) : "v"(addr));
#define ST1SC(addr, val) \
  asm volatile("global_store_dword %0, %1, off sc0 sc1" :: "v"(addr), "v"(val) : "memory");
#define ST4SC(addr, val) \
  asm volatile("global_store_dwordx4 %0, %1, off sc0 sc1" :: "v"(addr), "v"(val) : "memory");
#define WB3(a,b,c) asm volatile("s_waitcnt vmcnt(0)" : "+v"(a),"+v"(b),"+v"(c));
#define VMBAR8(a,b,c,d,e,f,g,h) \
  asm volatile("s_waitcnt vmcnt(0)" \
               : "+v"(a),"+v"(b),"+v"(c),"+v"(d),"+v"(e),"+v"(f),"+v"(g),"+v"(h));
#define LDSC(P, i) \
  asm volatile("global_load_dwordx4 %0, %1, off sc0 sc1" \
               : "=v"(pa##i) : "v"((P) + aoff + (i)*32)); \
  asm volatile("global_load_dwordx4 %0, %1, off sc0 sc1" \
               : "=v"(pb##i) : "v"((P) + aoff + (i)*32 + 4));
#define DECL_LOADS(P) \
  uint4v pa0,pa1,pa2,pa3,pa4,pa5,pa6,pa7,pa8,pa9,pa10,pa11,pa12,pa13,pa14,pa15; \
  uint4v pb0,pb1,pb2,pb3,pb4,pb5,pb6,pb7,pb8,pb9,pb10,pb11,pb12,pb13,pb14,pb15; \
  LDSC(P,0) LDSC(P,1) LDSC(P,2) LDSC(P,3) LDSC(P,4) LDSC(P,5) LDSC(P,6) LDSC(P,7) \
  LDSC(P,8) LDSC(P,9) LDSC(P,10) LDSC(P,11) LDSC(P,12) LDSC(P,13) LDSC(P,14) LDSC(P,15) \
  VMBAR8(pa0,pb0,pa1,pb1,pa2,pb2,pa3,pb3) \
  VMBAR8(pa4,pb4,pa5,pb5,pa6,pb6,pa7,pb7) \
  VMBAR8(pa8,pb8,pa9,pb9,pa10,pb10,pa11,pb11) \
  VMBAR8(pa12,pb12,pa13,pb13,pa14,pb14,pa15,pb15)

#define MS3(i) { \
  short8 AH_ = hi8(pa##i, pb##i); \
  short8 AL_ = lo8(pa##i, pb##i); \
  const int ko_ = (i)*32 + q*8; \
  short8 bh_ = *(const short8*)(&S.wpl[0][(col)*520 + ko_]); \
  short8 bl_ = *(const short8*)(&S.wpl[1][(col)*520 + ko_]); \
  acc0 = __builtin_amdgcn_mfma_f32_16x16x32_bf16(AH_, bh_, acc0, 0,0,0); \
  acc0 = __builtin_amdgcn_mfma_f32_16x16x32_bf16(AL_, bh_, acc0, 0,0,0); \
  acc0 = __builtin_amdgcn_mfma_f32_16x16x32_bf16(AH_, bl_, acc0, 0,0,0); \
  bh_ = *(const short8*)(&S.wpl[0][(16+col)*520 + ko_]); \
  bl_ = *(const short8*)(&S.wpl[1][(16+col)*520 + ko_]); \
  acc1 = __builtin_amdgcn_mfma_f32_16x16x32_bf16(AH_, bh_, acc1, 0,0,0); \
  acc1 = __builtin_amdgcn_mfma_f32_16x16x32_bf16(AL_, bh_, acc1, 0,0,0); \
  acc1 = __builtin_amdgcn_mfma_f32_16x16x32_bf16(AH_, bl_, acc1, 0,0,0); \
  bh_ = *(const short8*)(&S.wpl[0][(32+col)*520 + ko_]); \
  bl_ = *(const short8*)(&S.wpl[1][(32+col)*520 + ko_]); \
  acc2 = __builtin_amdgcn_mfma_f32_16x16x32_bf16(AH_, bh_, acc2, 0,0,0); \
  acc2 = __builtin_amdgcn_mfma_f32_16x16x32_bf16(AL_, bh_, acc2, 0,0,0); \
  acc2 = __builtin_amdgcn_mfma_f32_16x16x32_bf16(AH_, bl_, acc2, 0,0,0); }

#define MS1(i) { \
  short8 AH_ = hi8(pa##i, pb##i); \
  short8 AL_ = lo8(pa##i, pb##i); \
  const int ko_ = (i)*32 + q*8; \
  short8 bh_ = *(const short8*)(&S.wpl[0][(col)*520 + ko_]); \
  short8 bl_ = *(const short8*)(&S.wpl[1][(col)*520 + ko_]); \
  acc0 = __builtin_amdgcn_mfma_f32_16x16x32_bf16(AH_, bh_, acc0, 0,0,0); \
  acc0 = __builtin_amdgcn_mfma_f32_16x16x32_bf16(AL_, bh_, acc0, 0,0,0); \
  acc0 = __builtin_amdgcn_mfma_f32_16x16x32_bf16(AH_, bl_, acc0, 0,0,0); }

#define RUN16(M) M(0) M(1) M(2) M(3) M(4) M(5) M(6) M(7) \
                 M(8) M(9) M(10) M(11) M(12) M(13) M(14) M(15)

extern "C" __global__ void __launch_bounds__(NT, 1)
decoder_rnn(const float* __restrict__ ctx,   // [64][512]
            const float* __restrict__ Wih0,  // [1536][513] (row stride 513!)
            const float* __restrict__ Whh0,
            const float* __restrict__ bih0,
            const float* __restrict__ bhh0g,
            const float* __restrict__ Wih1,
            const float* __restrict__ Whh1,
            const float* __restrict__ bih1g,
            const float* __restrict__ bhh1g,
            const float* __restrict__ Wo1,
            const float* __restrict__ bo1g,
            const float* __restrict__ Wo2,
            const float* __restrict__ bo2g,
            float* __restrict__ out,         // [64*1024 y][65536 h_i]
            float* __restrict__ ws)
{
  extern __shared__ char smem_raw[];
  Smem& S = *reinterpret_cast<Smem*>(smem_raw);
  const int tid = threadIdx.x;
  const int wg  = blockIdx.x;

  uint*  hpk    = (uint*)ws;                 // h0pk 2x32768 | h1pk 32768
  float* gh1raw = (float*)ws + 98304;        // 32*3072
  float* yout   = (float*)ws + 196608;       // 2 x 2048
  int*   ibase  = (int*)((float*)ws + 200704);
  int*   gslots = ibase;                     // [128] gbar
  int*   epoch  = ibase + 128;
  int*   mbox   = ibase + 256;               // 128 lines x 32 ints (128B/line)

  const float bo2v = bo2g[0];

  // ---------------- init (swaps -> LLC; once, off critical path) ----------
  for (int i = wg*NT + tid; i < 200704; i += NWG*NT)
    SWP((uint*)ws + i, 0u);
  if (wg == 0)
    for (int i = tid; i < NWG*32; i += NT) SWP(mbox + i, 0);

  const int role = wg >> 5;
  const int j    = wg & 31;
  if (role != 3){
    const float* Wsrc = (role == 0) ? Whh0 : (role == 1) ? Whh1 : Wih1;
    for (int i = tid; i < 48*512; i += NT){
      int r = i >> 9, k = i & 511;
      int g = r >> 4, n = r & 15;
      float wv = Wsrc[(size_t)(g*512 + 16*j + n)*512 + k];
      ushort hh = bfrnd(wv);
      S.wpl[0][r*520 + k] = hh;
      S.wpl[1][r*520 + k] = bfrnd(wv - bf2f(hh));
    }
  } else {
    for (int i = tid; i < 16*512; i += NT){
      int r = i >> 9, k = i & 511;
      float wv = Wo1[(size_t)(16*j + r)*512 + k];
      ushort hh = bfrnd(wv);
      S.wpl[0][r*520 + k] = hh;
      S.wpl[1][r*520 + k] = bfrnd(wv - bf2f(hh));
    }
    if (tid < 16){ S.bo1v[tid] = bo1g[16*j + tid]; S.wo2v[tid] = Wo2[16*j + tid]; }
  }
  if (role == 0){
    if (tid < 48){
      int g = tid >> 4, n = tid & 15;
      S.wcol[g][n] = Wih0[(size_t)(g*512 + 16*j + n)*513 + 512];
    }
    if (tid < 16) S.bhnN[tid] = bhh0g[2*512 + 16*j + tid];
    for (int idx = tid; idx < 3072; idx += NT){
      int r = idx >> 6, b = idx & 63;
      int g = r >> 4, n = r & 15;
      int grow = g*512 + 16*j + n;
      const float* wr = Wih0 + (size_t)grow*513;
      const float* cx = ctx  + (size_t)b*512;
      float s = bih0[grow];
      if (g < 2) s += bhh0g[grow];
      #pragma unroll 4
      for (int k = 0; k < 512; ++k) s += wr[k]*cx[k];
      S.gictx[g*1088 + n*68 + b] = s;
    }
  }
  if (role == 2 && tid < 16){
    int n = tid;
    S.bsumR[n] = bih1g[16*j + n]       + bhh1g[16*j + n];
    S.bsumZ[n] = bih1g[512 + 16*j + n] + bhh1g[512 + 16*j + n];
    S.binN[n]  = bih1g[1024 + 16*j + n];
    S.bhnN[n]  = bhh1g[1024 + 16*j + n];
  }

  gbar(gslots, epoch, wg, tid, 1);

  int* myline = mbox + wg*32;

  const int v   = tid >> 6;
  const int l   = tid & 63;
  const int q   = l >> 4;
  const int col = l & 15;
  const int aoff = (16*v + col)*512 + q*8;
  const int b0w  = 16*v + 4*q;
  const int ng   = 16*j + col;

  if (role == 0){
    float hc0 = 0.f, hc1 = 0.f, hc2 = 0.f, hc3 = 0.f;   // carried h0-old
    for (int t = 0; t < TT; ++t){
      const int r0 = t & 1, w0 = r0 ^ 1;
      waitmail(myline + 0, 32*t, tid);       // h0[t-1] peers at LLC
      const uint* rP = hpk + r0*32768;
      uint*       wP = hpk + w0*32768;
      f32x4 acc0={0,0,0,0}, acc1={0,0,0,0}, acc2={0,0,0,0};
      DECL_LOADS(rP)
      RUN16(MS3)
      waitmail(myline + 1, 32*t, tid);       // y[t-1] partials at LLC
      if (tid < 64){
        float s = 0.f;
        if (t > 0){
          const float* yp = yout + ((t-1)&1)*2048 + tid;
          float vv[32];
          #pragma unroll
          for (int jj = 0; jj < 32; ++jj)
            LD1SCD(vv[jj], yp + jj*64)
          VMBAR8(vv[0],vv[1],vv[2],vv[3],vv[4],vv[5],vv[6],vv[7])
          VMBAR8(vv[8],vv[9],vv[10],vv[11],vv[12],vv[13],vv[14],vv[15])
          VMBAR8(vv[16],vv[17],vv[18],vv[19],vv[20],vv[21],vv[22],vv[23])
          VMBAR8(vv[24],vv[25],vv[26],vv[27],vv[28],vv[29],vv[30],vv[31])
          #pragma unroll
          for (int jj = 0; jj < 32; ++jj) s += vv[jj];
        }
        float pv = fmaxf(s + bo2v, 0.f);
        S.prevS[tid] = pv;
        if (wg == 0 && t > 0) out[(size_t)tid*TT + (t-1)] = pv;
      }
      __syncthreads();
      f32x4 pv4 = *(const f32x4*)&S.prevS[b0w];
      f32x4 gR = *(const f32x4*)&S.gictx[0*1088 + col*68 + b0w];
      f32x4 gZ = *(const f32x4*)&S.gictx[1*1088 + col*68 + b0w];
      f32x4 gN = *(const f32x4*)&S.gictx[2*1088 + col*68 + b0w];
      float wc0 = S.wcol[0][col], wc1 = S.wcol[1][col], wc2 = S.wcol[2][col];
      float bhn = S.bhnN[col];
      #define E0(i, HC) { \
        float rr = sigm(gR[i] + pv4[i]*wc0 + acc0[i]); \
        float zz = sigm(gZ[i] + pv4[i]*wc1 + acc1[i]); \
        float nn = tanhf(gN[i] + pv4[i]*wc2 + rr*(acc2[i] + bhn)); \
        float h = (1.f-zz)*nn + zz*HC; \
        HC = h; \
        ST1SC(wP + (size_t)(b0w+(i))*512 + ng, pkh(h)) }
      E0(0,hc0) E0(1,hc1) E0(2,hc2) E0(3,hc3)
      #undef E0
      drain_sync();
      if (tid < 64) FADDI(mbox + ((tid < 32) ? tid : tid + 32)*32 + 0);
    }
  } else if (role == 1){
    const uint* hp1 = hpk + 65536;
    for (int t = 0; t < TT; ++t){
      waitmail(myline + 0, 32*t, tid);       // h1[t-1] at LLC
      f32x4 acc0={0,0,0,0}, acc1={0,0,0,0}, acc2={0,0,0,0};
      DECL_LOADS(hp1)
      RUN16(MS3)
      float* gp = gh1raw + (size_t)j*3072 + v*256 + l*4;
      ST4SC(gp,        acc0)
      ST4SC(gp + 1024, acc1)
      ST4SC(gp + 2048, acc2)
      drain_sync();
      if (tid < 32) FADDI(mbox + (64 + tid)*32 + 1);
    }
  } else if (role == 2){
    uint* p1 = hpk + 65536;
    float hc0 = 0.f, hc1 = 0.f, hc2 = 0.f, hc3 = 0.f;   // carried h1-old
    for (int t = 0; t < TT; ++t){
      const int w0 = (t & 1) ^ 1;
      waitmail(myline + 0, 32*(t+1), tid);   // h0[t] at LLC
      waitmail(myline + 1, 32*(t+1), tid);   // gh1[t] (one step slack: ~free)
      const uint* rP = hpk + w0*32768;
      const float* gp = gh1raw + (size_t)j*3072 + v*256 + l*4;
      // issue gh1 loads first; they complete under DECL_LOADS' vmcnt(0)
      uint4v hRv, hZv, hNv;
      LD1SC(hRv, (const uint*)(gp + 0))
      LD1SC(hZv, (const uint*)(gp + 1024))
      LD1SC(hNv, (const uint*)(gp + 2048))
      f32x4 acc0={0,0,0,0}, acc1={0,0,0,0}, acc2={0,0,0,0};
      DECL_LOADS(rP)
      WB3(hRv, hZv, hNv)
      RUN16(MS3)
      f32x4 hR = __builtin_bit_cast(f32x4, hRv);
      f32x4 hZ = __builtin_bit_cast(f32x4, hZv);
      f32x4 hN = __builtin_bit_cast(f32x4, hNv);
      float bsR = S.bsumR[col], bsZ = S.bsumZ[col], biN = S.binN[col], bhN = S.bhnN[col];
      #define E1(i, HC) { \
        float r1 = sigm(acc0[i] + hR[i] + bsR); \
        float z1 = sigm(acc1[i] + hZ[i] + bsZ); \
        float n1 = tanhf(acc2[i] + biN + r1*(hN[i] + bhN)); \
        float h = (1.f-z1)*n1 + z1*HC; \
        HC = h; \
        ST1SC(p1 + (size_t)(b0w+(i))*512 + ng, pkh(h)) }
      E1(0,hc0) E1(1,hc1) E1(2,hc2) E1(3,hc3)
      #undef E1
      drain_sync();
      if (tid < 64) FADDI(mbox + ((tid < 32) ? (96 + tid) : tid)*32 + 0);
    }
  } else {
    const uint* hp1 = hpk + 65536;
    for (int t = 0; t < TT; ++t){
      waitmail(myline + 0, 32*(t+1), tid);   // h1[t] at LLC
      f32x4 acc0={0,0,0,0};
      DECL_LOADS(hp1)
      RUN16(MS1)
      float s0 = S.wo2v[col]*fmaxf(acc0[0] + S.bo1v[col], 0.f);
      float s1 = S.wo2v[col]*fmaxf(acc0[1] + S.bo1v[col], 0.f);
      float s2 = S.wo2v[col]*fmaxf(acc0[2] + S.bo1v[col], 0.f);
      float s3 = S.wo2v[col]*fmaxf(acc0[3] + S.bo1v[col], 0.f);
      #pragma unroll
      for (int d = 1; d < 16; d <<= 1){
        s0 += __shfl_xor(s0, d);
        s1 += __shfl_xor(s1, d);
        s2 += __shfl_xor(s2, d);
        s3 += __shfl_xor(s3, d);
      }
      if (col == 0){
        float* rp = yout + (t&1)*2048 + j*64 + b0w;
        f32x4 sv = {s0, s1, s2, s3};
        ST4SC(rp, sv)
      }
      drain_sync();
      if (tid < 32) FADDI(mbox + tid*32 + 1);
    }
  }

  // ---------------- finale: one global release/acquire barrier ------------
  gbar(gslots, epoch, wg, tid, 2);
  if (wg == 0 && tid < 64){
    float s = 0.f;
    const float* yp = yout + 2048 + tid;     // parity of t=1023 is 1
    #pragma unroll
    for (int jj = 0; jj < 32; ++jj) s += ALDF(yp + jj*64);
    out[(size_t)tid*TT + 1023] = fmaxf(s + bo2v, 0.f);
  }
  #pragma unroll
  for (int k = 0; k < 2; ++k){
    int g = wg*512 + k*256 + tid;
    if (g < 32768) out[65536 + g] = unpk(hpk[g]);            // h0 final in buf0
    else           out[65536 + g] = unpk(hpk[65536 + (g - 32768)]);
  }
}

extern "C" void kernel_launch(void* const* d_in, const int* in_sizes, int n_in,
                              void* d_out, int out_size, void* d_ws, size_t ws_size,
                              hipStream_t stream){
  const float* ctx   = (const float*)d_in[0];
  const float* Wih0  = (const float*)d_in[2];
  const float* Whh0  = (const float*)d_in[3];
  const float* bih0  = (const float*)d_in[4];
  const float* bhh0  = (const float*)d_in[5];
  const float* Wih1  = (const float*)d_in[6];
  const float* Whh1  = (const float*)d_in[7];
  const float* bih1  = (const float*)d_in[8];
  const float* bhh1  = (const float*)d_in[9];
  const float* Wo1   = (const float*)d_in[10];
  const float* bo1   = (const float*)d_in[11];
  const float* Wo2   = (const float*)d_in[12];
  const float* bo2   = (const float*)d_in[13];

  (void)in_sizes; (void)n_in; (void)out_size; (void)ws_size;

  (void)hipFuncSetAttribute((const void*)decoder_rnn,
                            hipFuncAttributeMaxDynamicSharedMemorySize,
                            (int)sizeof(Smem));

  decoder_rnn<<<NWG, NT, sizeof(Smem), stream>>>(
      ctx, Wih0, Whh0, bih0, bhh0, Wih1, Whh1, bih1, bhh1,
      Wo1, bo1, Wo2, bo2, (float*)d_out, (float*)d_ws);
}

// Round 4
// 12555.142 us; speedup vs baseline: 1.3990x; 1.3754x over previous
//
#include <hip/hip_runtime.h>
#include <stdint.h>

// DecoderRNN R19: planar hi/lo bf16 h-planes + hi-only transport on the two
// CRITICAL hops (role2: h0->h1 input path; role3: h1->y path), full hi/lo on
// the slack-funded self-recurrence paths (role0: Whh0@h0; role1: Whh1@h1).
//  R16/R17/R18 nulls killed the protocol/traffic theories; hop anatomy is
//  balanced: load 1.3 + MFMA 1.4 + EW 0.25 + protocol 1.0 per hop. This round
//  shrinks load (128->64KB) AND MFMA (144->96 / 48->32) AND EW (fast
//  exp/tanh) on the critical hops simultaneously.
//  fp32 GRU state stays register-carried (hc) - transport quantization does
//  not compound in the state itself.
//  Planar layout also removes all hi8/lo8 perm ops (A-frags load directly).
//  Flags/drains/mailboxes byte-identical to R15/R18 discipline.
// Plane map (ushort units in ws): h0hi[2] @ 0/32768, h0lo[2] @ 65536/98304,
//  h1hi @ 131072, h1lo @ 163840  (= old 384KB hpk region exactly).

#define NWG 128
#define NT  256
#define TT  1024

typedef unsigned short ushort;
typedef unsigned int   uint;
typedef __attribute__((ext_vector_type(8))) short short8;
typedef __attribute__((ext_vector_type(4))) float f32x4;
typedef __attribute__((ext_vector_type(4))) uint  uint4v;

struct __align__(16) Smem {
  ushort wpl[2][48*520];
  float  gictx[3*16*68];
  float  wcol[3][16];
  float  bsumR[16], bsumZ[16], binN[16], bhnN[16];
  float  bo1v[16], wo2v[16];
  float  prevS[64];
};

__device__ __forceinline__ float frcp(float x){
#if __has_builtin(__builtin_amdgcn_rcpf)
  return __builtin_amdgcn_rcpf(x);
#else
  return 1.f/x;
#endif
}
// fast sigmoid/tanh via v_exp_f32; exact at +-inf tails (no NaN)
__device__ __forceinline__ float sigm(float x){ return frcp(1.f + __expf(-x)); }
__device__ __forceinline__ float tanh_f(float x){
  return 1.f - 2.f*frcp(__expf(2.f*x) + 1.f);
}
__device__ __forceinline__ float bf2f(ushort h){ return __uint_as_float(((uint)h)<<16); }
__device__ __forceinline__ ushort bfrnd(float x){
  uint u = __float_as_uint(x);
  return (ushort)((u + 0x7fffu + ((u>>16)&1u)) >> 16);
}
#define SWP(p, v)  (void)__hip_atomic_exchange((uint*)(p), (uint)(v), __ATOMIC_RELAXED, __HIP_MEMORY_SCOPE_AGENT)
#define ALD1(p)    __hip_atomic_load((const uint*)(p), __ATOMIC_RELAXED, __HIP_MEMORY_SCOPE_AGENT)
#define ALDF(p)    __uint_as_float(ALD1(p))
#define FADDI(p)   (void)__hip_atomic_fetch_add((p), 1, __ATOMIC_RELAXED, __HIP_MEMORY_SCOPE_AGENT)

// init/final global barrier (epoch-monotonic)
__device__ __forceinline__ void gbar(int* slots, int* epoch, int w, int tid, int e){
  __syncthreads();
  if (tid == 0)
    __hip_atomic_store(&slots[w], e, __ATOMIC_RELEASE, __HIP_MEMORY_SCOPE_AGENT);
  if (w == 0 && tid < 64){
    for(;;){
      int m0 = __hip_atomic_load(&slots[tid*2+0], __ATOMIC_RELAXED, __HIP_MEMORY_SCOPE_AGENT);
      int m1 = __hip_atomic_load(&slots[tid*2+1], __ATOMIC_RELAXED, __HIP_MEMORY_SCOPE_AGENT);
      if (__all(min(m0,m1) >= e)) break;
      __builtin_amdgcn_s_sleep(1);
    }
    if (tid == 0){
      __builtin_amdgcn_fence(__ATOMIC_ACQUIRE, "agent");
      __hip_atomic_store(epoch, e, __ATOMIC_RELEASE, __HIP_MEMORY_SCOPE_AGENT);
    }
  }
  if (tid == 0){
    while (__hip_atomic_load(epoch, __ATOMIC_RELAXED, __HIP_MEMORY_SCOPE_AGENT) < e)
      __builtin_amdgcn_s_sleep(1);
    __builtin_amdgcn_fence(__ATOMIC_ACQUIRE, "agent");
  }
  __syncthreads();
}

__device__ __forceinline__ void drain_sync(){
  __builtin_amdgcn_s_waitcnt(0);
  __syncthreads();
}
// consumer poll: 1 lane, busy (dependent RTT-paced loads; no sleep quantum)
__device__ __forceinline__ void waitmail(const int* w, int target, int tid){
  if (tid == 0)
    while ((int)ALD1(w) < target) {}
  __syncthreads();
}

// coherent LLC-direct ops (sc0 sc1 = bypass L1+L2, coalesced)
#define LD1SC(dst, addr) \
  asm volatile("global_load_dwordx4 %0, %1, off sc0 sc1" : "=v"(dst) : "v"(addr));
#define LD1SCD(dst, addr) \
  asm volatile("global_load_dword %0, %1, off sc0 sc1" : "=v"(dst) : "v"(addr));
#define STSH(addr, val) \
  asm volatile("global_store_short %0, %1, off sc0 sc1" :: "v"(addr), "v"(val) : "memory");
#define ST4SC(addr, val) \
  asm volatile("global_store_dwordx4 %0, %1, off sc0 sc1" :: "v"(addr), "v"(val) : "memory");
#define WB3(a,b,c) asm volatile("s_waitcnt vmcnt(0)" : "+v"(a),"+v"(b),"+v"(c));
#define VMBAR8(a,b,c,d,e,f,g,h) \
  asm volatile("s_waitcnt vmcnt(0)" \
               : "+v"(a),"+v"(b),"+v"(c),"+v"(d),"+v"(e),"+v"(f),"+v"(g),"+v"(h));

// planar A-frag loads: plane P (ushort*), lane row 16v+col, k = i*32+q*8
#define LDH(P, i) \
  asm volatile("global_load_dwordx4 %0, %1, off sc0 sc1" \
               : "=v"(ha##i) : "v"((P) + aoffB + (i)*32));
#define LDL(P, i) \
  asm volatile("global_load_dwordx4 %0, %1, off sc0 sc1" \
               : "=v"(la##i) : "v"((P) + aoffB + (i)*32));

#define DECL_HI(P) \
  uint4v ha0,ha1,ha2,ha3,ha4,ha5,ha6,ha7,ha8,ha9,ha10,ha11,ha12,ha13,ha14,ha15; \
  LDH(P,0) LDH(P,1) LDH(P,2) LDH(P,3) LDH(P,4) LDH(P,5) LDH(P,6) LDH(P,7) \
  LDH(P,8) LDH(P,9) LDH(P,10) LDH(P,11) LDH(P,12) LDH(P,13) LDH(P,14) LDH(P,15) \
  VMBAR8(ha0,ha1,ha2,ha3,ha4,ha5,ha6,ha7) \
  VMBAR8(ha8,ha9,ha10,ha11,ha12,ha13,ha14,ha15)

#define DECL_HILO(PH, PL) \
  uint4v ha0,ha1,ha2,ha3,ha4,ha5,ha6,ha7,ha8,ha9,ha10,ha11,ha12,ha13,ha14,ha15; \
  uint4v la0,la1,la2,la3,la4,la5,la6,la7,la8,la9,la10,la11,la12,la13,la14,la15; \
  LDH(PH,0) LDH(PH,1) LDH(PH,2) LDH(PH,3) LDH(PH,4) LDH(PH,5) LDH(PH,6) LDH(PH,7) \
  LDH(PH,8) LDH(PH,9) LDH(PH,10) LDH(PH,11) LDH(PH,12) LDH(PH,13) LDH(PH,14) LDH(PH,15) \
  LDL(PL,0) LDL(PL,1) LDL(PL,2) LDL(PL,3) LDL(PL,4) LDL(PL,5) LDL(PL,6) LDL(PL,7) \
  LDL(PL,8) LDL(PL,9) LDL(PL,10) LDL(PL,11) LDL(PL,12) LDL(PL,13) LDL(PL,14) LDL(PL,15) \
  VMBAR8(ha0,ha1,ha2,ha3,ha4,ha5,ha6,ha7) \
  VMBAR8(ha8,ha9,ha10,ha11,ha12,ha13,ha14,ha15) \
  VMBAR8(la0,la1,la2,la3,la4,la5,la6,la7) \
  VMBAR8(la8,la9,la10,la11,la12,la13,la14,la15)

#define MFMA_ __builtin_amdgcn_mfma_f32_16x16x32_bf16

// full precision (roles 0/1): 9 MFMAs per i (AHbh, ALbh, AHbl per gate)
#define MS3F(i) { \
  short8 AH_ = __builtin_bit_cast(short8, ha##i); \
  short8 AL_ = __builtin_bit_cast(short8, la##i); \
  const int ko_ = (i)*32 + q*8; \
  short8 bh_ = *(const short8*)(&S.wpl[0][(col)*520 + ko_]); \
  short8 bl_ = *(const short8*)(&S.wpl[1][(col)*520 + ko_]); \
  acc0 = MFMA_(AH_, bh_, acc0, 0,0,0); \
  acc0 = MFMA_(AL_, bh_, acc0, 0,0,0); \
  acc0 = MFMA_(AH_, bl_, acc0, 0,0,0); \
  bh_ = *(const short8*)(&S.wpl[0][(16+col)*520 + ko_]); \
  bl_ = *(const short8*)(&S.wpl[1][(16+col)*520 + ko_]); \
  acc1 = MFMA_(AH_, bh_, acc1, 0,0,0); \
  acc1 = MFMA_(AL_, bh_, acc1, 0,0,0); \
  acc1 = MFMA_(AH_, bl_, acc1, 0,0,0); \
  bh_ = *(const short8*)(&S.wpl[0][(32+col)*520 + ko_]); \
  bl_ = *(const short8*)(&S.wpl[1][(32+col)*520 + ko_]); \
  acc2 = MFMA_(AH_, bh_, acc2, 0,0,0); \
  acc2 = MFMA_(AL_, bh_, acc2, 0,0,0); \
  acc2 = MFMA_(AH_, bl_, acc2, 0,0,0); }

// hi-only A (role 2): 6 MFMAs per i (AHbh, AHbl per gate)
#define MS3H(i) { \
  short8 AH_ = __builtin_bit_cast(short8, ha##i); \
  const int ko_ = (i)*32 + q*8; \
  short8 bh_ = *(const short8*)(&S.wpl[0][(col)*520 + ko_]); \
  short8 bl_ = *(const short8*)(&S.wpl[1][(col)*520 + ko_]); \
  acc0 = MFMA_(AH_, bh_, acc0, 0,0,0); \
  acc0 = MFMA_(AH_, bl_, acc0, 0,0,0); \
  bh_ = *(const short8*)(&S.wpl[0][(16+col)*520 + ko_]); \
  bl_ = *(const short8*)(&S.wpl[1][(16+col)*520 + ko_]); \
  acc1 = MFMA_(AH_, bh_, acc1, 0,0,0); \
  acc1 = MFMA_(AH_, bl_, acc1, 0,0,0); \
  bh_ = *(const short8*)(&S.wpl[0][(32+col)*520 + ko_]); \
  bl_ = *(const short8*)(&S.wpl[1][(32+col)*520 + ko_]); \
  acc2 = MFMA_(AH_, bh_, acc2, 0,0,0); \
  acc2 = MFMA_(AH_, bl_, acc2, 0,0,0); }

// hi-only A, single output block (role 3): 2 MFMAs per i
#define MS1H(i) { \
  short8 AH_ = __builtin_bit_cast(short8, ha##i); \
  const int ko_ = (i)*32 + q*8; \
  short8 bh_ = *(const short8*)(&S.wpl[0][(col)*520 + ko_]); \
  short8 bl_ = *(const short8*)(&S.wpl[1][(col)*520 + ko_]); \
  acc0 = MFMA_(AH_, bh_, acc0, 0,0,0); \
  acc0 = MFMA_(AH_, bl_, acc0, 0,0,0); }

#define RUN16(M) M(0) M(1) M(2) M(3) M(4) M(5) M(6) M(7) \
                 M(8) M(9) M(10) M(11) M(12) M(13) M(14) M(15)

extern "C" __global__ void __launch_bounds__(NT, 1)
decoder_rnn(const float* __restrict__ ctx,   // [64][512]
            const float* __restrict__ Wih0,  // [1536][513] (row stride 513!)
            const float* __restrict__ Whh0,
            const float* __restrict__ bih0,
            const float* __restrict__ bhh0g,
            const float* __restrict__ Wih1,
            const float* __restrict__ Whh1,
            const float* __restrict__ bih1g,
            const float* __restrict__ bhh1g,
            const float* __restrict__ Wo1,
            const float* __restrict__ bo1g,
            const float* __restrict__ Wo2,
            const float* __restrict__ bo2g,
            float* __restrict__ out,         // [64*1024 y][65536 h_i]
            float* __restrict__ ws)
{
  extern __shared__ char smem_raw[];
  Smem& S = *reinterpret_cast<Smem*>(smem_raw);
  const int tid = threadIdx.x;
  const int wg  = blockIdx.x;

  ushort* hp    = (ushort*)ws;               // planes: see header map
  float* gh1raw = (float*)ws + 98304;        // 32*3072
  float* yout   = (float*)ws + 196608;       // 2 x 2048
  int*   ibase  = (int*)((float*)ws + 200704);
  int*   gslots = ibase;                     // [128] gbar
  int*   epoch  = ibase + 128;
  int*   mbox   = ibase + 256;               // 128 lines x 32 ints (128B/line)

  const float bo2v = bo2g[0];

  // ---------------- init (swaps -> LLC; once, off critical path) ----------
  for (int i = wg*NT + tid; i < 200704; i += NWG*NT)
    SWP((uint*)ws + i, 0u);
  if (wg == 0)
    for (int i = tid; i < NWG*32; i += NT) SWP(mbox + i, 0);

  const int role = wg >> 5;
  const int j    = wg & 31;
  if (role != 3){
    const float* Wsrc = (role == 0) ? Whh0 : (role == 1) ? Whh1 : Wih1;
    for (int i = tid; i < 48*512; i += NT){
      int r = i >> 9, k = i & 511;
      int g = r >> 4, n = r & 15;
      float wv = Wsrc[(size_t)(g*512 + 16*j + n)*512 + k];
      ushort hh = bfrnd(wv);
      S.wpl[0][r*520 + k] = hh;
      S.wpl[1][r*520 + k] = bfrnd(wv - bf2f(hh));
    }
  } else {
    for (int i = tid; i < 16*512; i += NT){
      int r = i >> 9, k = i & 511;
      float wv = Wo1[(size_t)(16*j + r)*512 + k];
      ushort hh = bfrnd(wv);
      S.wpl[0][r*520 + k] = hh;
      S.wpl[1][r*520 + k] = bfrnd(wv - bf2f(hh));
    }
    if (tid < 16){ S.bo1v[tid] = bo1g[16*j + tid]; S.wo2v[tid] = Wo2[16*j + tid]; }
  }
  if (role == 0){
    if (tid < 48){
      int g = tid >> 4, n = tid & 15;
      S.wcol[g][n] = Wih0[(size_t)(g*512 + 16*j + n)*513 + 512];
    }
    if (tid < 16) S.bhnN[tid] = bhh0g[2*512 + 16*j + tid];
    for (int idx = tid; idx < 3072; idx += NT){
      int r = idx >> 6, b = idx & 63;
      int g = r >> 4, n = r & 15;
      int grow = g*512 + 16*j + n;
      const float* wr = Wih0 + (size_t)grow*513;
      const float* cx = ctx  + (size_t)b*512;
      float s = bih0[grow];
      if (g < 2) s += bhh0g[grow];
      #pragma unroll 4
      for (int k = 0; k < 512; ++k) s += wr[k]*cx[k];
      S.gictx[g*1088 + n*68 + b] = s;
    }
  }
  if (role == 2 && tid < 16){
    int n = tid;
    S.bsumR[n] = bih1g[16*j + n]       + bhh1g[16*j + n];
    S.bsumZ[n] = bih1g[512 + 16*j + n] + bhh1g[512 + 16*j + n];
    S.binN[n]  = bih1g[1024 + 16*j + n];
    S.bhnN[n]  = bhh1g[1024 + 16*j + n];
  }

  gbar(gslots, epoch, wg, tid, 1);

  int* myline = mbox + wg*32;

  const int v   = tid >> 6;
  const int l   = tid & 63;
  const int q   = l >> 4;
  const int col = l & 15;
  const int aoffB = (16*v + col)*512 + q*8;   // ushort units within a plane
  const int b0w  = 16*v + 4*q;
  const int ng   = 16*j + col;

  if (role == 0){
    float hc0 = 0.f, hc1 = 0.f, hc2 = 0.f, hc3 = 0.f;   // carried h0-old (fp32)
    for (int t = 0; t < TT; ++t){
      const int r0 = t & 1, w0 = r0 ^ 1;
      waitmail(myline + 0, 32*t, tid);       // h0[t-1] peers at LLC
      const ushort* rH = hp + r0*32768;
      const ushort* rL = hp + 65536 + r0*32768;
      ushort*       wH = hp + w0*32768;
      ushort*       wL = hp + 65536 + w0*32768;
      f32x4 acc0={0,0,0,0}, acc1={0,0,0,0}, acc2={0,0,0,0};
      DECL_HILO(rH, rL)
      RUN16(MS3F)
      waitmail(myline + 1, 32*t, tid);       // y[t-1] partials at LLC
      if (tid < 64){
        float s = 0.f;
        if (t > 0){
          const float* yp = yout + ((t-1)&1)*2048 + tid;
          float vv[32];
          #pragma unroll
          for (int jj = 0; jj < 32; ++jj)
            LD1SCD(vv[jj], yp + jj*64)
          VMBAR8(vv[0],vv[1],vv[2],vv[3],vv[4],vv[5],vv[6],vv[7])
          VMBAR8(vv[8],vv[9],vv[10],vv[11],vv[12],vv[13],vv[14],vv[15])
          VMBAR8(vv[16],vv[17],vv[18],vv[19],vv[20],vv[21],vv[22],vv[23])
          VMBAR8(vv[24],vv[25],vv[26],vv[27],vv[28],vv[29],vv[30],vv[31])
          #pragma unroll
          for (int jj = 0; jj < 32; ++jj) s += vv[jj];
        }
        float pv = fmaxf(s + bo2v, 0.f);
        S.prevS[tid] = pv;
        if (wg == 0 && t > 0) out[(size_t)tid*TT + (t-1)] = pv;
      }
      __syncthreads();
      f32x4 pv4 = *(const f32x4*)&S.prevS[b0w];
      f32x4 gR = *(const f32x4*)&S.gictx[0*1088 + col*68 + b0w];
      f32x4 gZ = *(const f32x4*)&S.gictx[1*1088 + col*68 + b0w];
      f32x4 gN = *(const f32x4*)&S.gictx[2*1088 + col*68 + b0w];
      float wc0 = S.wcol[0][col], wc1 = S.wcol[1][col], wc2 = S.wcol[2][col];
      float bhn = S.bhnN[col];
      #define E0(i, HC) { \
        float rr = sigm(gR[i] + pv4[i]*wc0 + acc0[i]); \
        float zz = sigm(gZ[i] + pv4[i]*wc1 + acc1[i]); \
        float nn = tanh_f(gN[i] + pv4[i]*wc2 + rr*(acc2[i] + bhn)); \
        float h = (1.f-zz)*nn + zz*HC; \
        HC = h; \
        ushort hh_ = bfrnd(h); \
        uint hu_ = hh_, lu_ = bfrnd(h - bf2f(hh_)); \
        STSH(wH + (size_t)(b0w+(i))*512 + ng, hu_) \
        STSH(wL + (size_t)(b0w+(i))*512 + ng, lu_) }
      E0(0,hc0) E0(1,hc1) E0(2,hc2) E0(3,hc3)
      #undef E0
      drain_sync();
      if (tid < 64) FADDI(mbox + ((tid < 32) ? tid : tid + 32)*32 + 0);
    }
  } else if (role == 1){
    const ushort* rH = hp + 131072;          // h1 hi plane
    const ushort* rL = hp + 163840;          // h1 lo plane
    for (int t = 0; t < TT; ++t){
      waitmail(myline + 0, 32*t, tid);       // h1[t-1] at LLC
      f32x4 acc0={0,0,0,0}, acc1={0,0,0,0}, acc2={0,0,0,0};
      DECL_HILO(rH, rL)
      RUN16(MS3F)
      float* gp = gh1raw + (size_t)j*3072 + v*256 + l*4;
      ST4SC(gp,        acc0)
      ST4SC(gp + 1024, acc1)
      ST4SC(gp + 2048, acc2)
      drain_sync();
      if (tid < 32) FADDI(mbox + (64 + tid)*32 + 1);
    }
  } else if (role == 2){
    ushort* p1H = hp + 131072;
    ushort* p1L = hp + 163840;
    float hc0 = 0.f, hc1 = 0.f, hc2 = 0.f, hc3 = 0.f;   // carried h1-old (fp32)
    for (int t = 0; t < TT; ++t){
      const int w0 = (t & 1) ^ 1;
      waitmail(myline + 0, 32*(t+1), tid);   // h0[t] at LLC
      waitmail(myline + 1, 32*(t+1), tid);   // gh1[t] (one step slack: ~free)
      const ushort* rH = hp + w0*32768;      // h0[t] hi plane ONLY (critical)
      const float* gp = gh1raw + (size_t)j*3072 + v*256 + l*4;
      // issue gh1 loads first; they complete under DECL_HI's vmcnt(0)
      uint4v hRv, hZv, hNv;
      LD1SC(hRv, (const uint*)(gp + 0))
      LD1SC(hZv, (const uint*)(gp + 1024))
      LD1SC(hNv, (const uint*)(gp + 2048))
      f32x4 acc0={0,0,0,0}, acc1={0,0,0,0}, acc2={0,0,0,0};
      DECL_HI(rH)
      WB3(hRv, hZv, hNv)
      RUN16(MS3H)
      f32x4 hR = __builtin_bit_cast(f32x4, hRv);
      f32x4 hZ = __builtin_bit_cast(f32x4, hZv);
      f32x4 hN = __builtin_bit_cast(f32x4, hNv);
      float bsR = S.bsumR[col], bsZ = S.bsumZ[col], biN = S.binN[col], bhN = S.bhnN[col];
      #define E1(i, HC) { \
        float r1 = sigm(acc0[i] + hR[i] + bsR); \
        float z1 = sigm(acc1[i] + hZ[i] + bsZ); \
        float n1 = tanh_f(acc2[i] + biN + r1*(hN[i] + bhN)); \
        float h = (1.f-z1)*n1 + z1*HC; \
        HC = h; \
        ushort hh_ = bfrnd(h); \
        uint hu_ = hh_, lu_ = bfrnd(h - bf2f(hh_)); \
        STSH(p1H + (size_t)(b0w+(i))*512 + ng, hu_) \
        STSH(p1L + (size_t)(b0w+(i))*512 + ng, lu_) }
      E1(0,hc0) E1(1,hc1) E1(2,hc2) E1(3,hc3)
      #undef E1
      drain_sync();
      if (tid < 64) FADDI(mbox + ((tid < 32) ? (96 + tid) : tid)*32 + 0);
    }
  } else {
    const ushort* rH = hp + 131072;          // h1 hi plane ONLY (critical)
    for (int t = 0; t < TT; ++t){
      waitmail(myline + 0, 32*(t+1), tid);   // h1[t] at LLC
      f32x4 acc0={0,0,0,0};
      DECL_HI(rH)
      RUN16(MS1H)
      float s0 = S.wo2v[col]*fmaxf(acc0[0] + S.bo1v[col], 0.f);
      float s1 = S.wo2v[col]*fmaxf(acc0[1] + S.bo1v[col], 0.f);
      float s2 = S.wo2v[col]*fmaxf(acc0[2] + S.bo1v[col], 0.f);
      float s3 = S.wo2v[col]*fmaxf(acc0[3] + S.bo1v[col], 0.f);
      #pragma unroll
      for (int d = 1; d < 16; d <<= 1){
        s0 += __shfl_xor(s0, d);
        s1 += __shfl_xor(s1, d);
        s2 += __shfl_xor(s2, d);
        s3 += __shfl_xor(s3, d);
      }
      if (col == 0){
        float* rp = yout + (t&1)*2048 + j*64 + b0w;
        f32x4 sv = {s0, s1, s2, s3};
        ST4SC(rp, sv)
      }
      drain_sync();
      if (tid < 32) FADDI(mbox + tid*32 + 1);
    }
  }

  // ---------------- finale: one global release/acquire barrier ------------
  gbar(gslots, epoch, wg, tid, 2);
  if (wg == 0 && tid < 64){
    float s = 0.f;
    const float* yp = yout + 2048 + tid;     // parity of t=1023 is 1
    #pragma unroll
    for (int jj = 0; jj < 32; ++jj) s += ALDF(yp + jj*64);
    out[(size_t)tid*TT + 1023] = fmaxf(s + bo2v, 0.f);
  }
  #pragma unroll
  for (int k = 0; k < 2; ++k){
    int g = wg*512 + k*256 + tid;
    if (g < 32768){                          // h0 final in buf0 planes
      out[65536 + g] = bf2f(hp[g]) + bf2f(hp[65536 + g]);
    } else {
      int g2 = g - 32768;                    // h1 planes
      out[65536 + g] = bf2f(hp[131072 + g2]) + bf2f(hp[163840 + g2]);
    }
  }
}

extern "C" void kernel_launch(void* const* d_in, const int* in_sizes, int n_in,
                              void* d_out, int out_size, void* d_ws, size_t ws_size,
                              hipStream_t stream){
  const float* ctx   = (const float*)d_in[0];
  const float* Wih0  = (const float*)d_in[2];
  const float* Whh0  = (const float*)d_in[3];
  const float* bih0  = (const float*)d_in[4];
  const float* bhh0  = (const float*)d_in[5];
  const float* Wih1  = (const float*)d_in[6];
  const float* Whh1  = (const float*)d_in[7];
  const float* bih1  = (const float*)d_in[8];
  const float* bhh1  = (const float*)d_in[9];
  const float* Wo1   = (const float*)d_in[10];
  const float* bo1   = (const float*)d_in[11];
  const float* Wo2   = (const float*)d_in[12];
  const float* bo2   = (const float*)d_in[13];

  (void)in_sizes; (void)n_in; (void)out_size; (void)ws_size;

  (void)hipFuncSetAttribute((const void*)decoder_rnn,
                            hipFuncAttributeMaxDynamicSharedMemorySize,
                            (int)sizeof(Smem));

  decoder_rnn<<<NWG, NT, sizeof(Smem), stream>>>(
      ctx, Wih0, Whh0, bih0, bhh0, Wih1, Whh1, bih1, bhh1,
      Wo1, bo1, Wo2, bo2, (float*)d_out, (float*)d_ws);
}